// Round 8
// baseline (150.504 us; speedup 1.0000x reference)
//
#include <hip/hip_runtime.h>

// QNet forward, MI355X — R8: 16B global_load_lds staging everywhere.
// B=65536 rows, obs=1129 (37 self + 39*28 others).
// 256 thr (4 waves), 64 rows/block (16/wave), grid 1024, 3 blocks/CU (~53.5KB LDS).
//
// R7 post-mortem: ~670 vmem instrs/wave, mostly 4B glds4 (256B/instr); per-CU
// streaming stuck at ~5.7 B/cy (copy ceiling 10.2). R8 cuts vmem instrs 3x:
//  - pass 1 A: 2x glds16/chunk, tri-buffered (lead 2), linear LDS dest with
//    (row=lane&15, quad=lane>>4) source mapping; reads = 2x b128/chunk at
//    offA0, offA0+256 (bank-optimal: 32 banks x 8 accesses, structural min).
//  - pass 1 B: 2x glds16/wave/chunk, tri-buffered (unchanged layout).
//  - pass 2: 4x glds16/pair (4KB window, 16 chunks), wave-private dbuf;
//    agent frags at oP00/oP00+256 (a=0) and oP10/oP11 (a=1).
//  - counted vmcnt(4) sync everywhere; never drain to 0 in steady loops.
// Chunk-addr formula: addr(row,c4) = (c4>>2)*1024 + (c4&3)*256 + row*16.
//
// Fragment maps (gfx950 16x16x32 bf16): A/B: row|col = lane&15, k = 8*(lane>>4)+i
//   C/D: col = lane&15, row = 4*(lane>>4) + reg
// Split-bf16: 3-term logits/self/head, 2-term others.
//
// d_ws: 120 units of 128 bf16x8 (64 hi + 64 lo), 2KB each.
//   W_al: c*3+t | W_self: 108+c*2+t | W_oth'(K=32, leading zero row): 112+t
//   W_ao: 114+t | W_emb: 116+t | W_out: 118+t

typedef __bf16 bf16x8 __attribute__((ext_vector_type(8)));
typedef float  f32x4  __attribute__((ext_vector_type(4)));

constexpr int OBS = 1129;

#define MFMA(a, b, c) __builtin_amdgcn_mfma_f32_16x16x32_bf16((a), (b), (c), 0, 0, 0)

__device__ __forceinline__ float4 ld4(const float* p) {
    float4 v;
    __builtin_memcpy(&v, p, 16);
    return v;
}

__device__ __forceinline__ void split8(const float* a, bf16x8& h, bf16x8& l) {
#pragma unroll
    for (int i = 0; i < 8; ++i) {
        __bf16 hb = (__bf16)a[i];
        h[i] = hb;
        l[i] = (__bf16)(a[i] - (float)hb);
    }
}

__device__ __forceinline__ f32x4 mm3(bf16x8 ah, bf16x8 al, bf16x8 bh, bf16x8 bl, f32x4 c) {
    c = MFMA(ah, bh, c);
    c = MFMA(ah, bl, c);
    c = MFMA(al, bh, c);
    return c;
}

__device__ __forceinline__ void glds16(const void* g, void* l) {
    __builtin_amdgcn_global_load_lds((const __attribute__((address_space(1))) void*)g,
                                     (__attribute__((address_space(3))) void*)l, 16, 0, 0);
}

// ---------------- prep: split weights into fragment order ----------------
__global__ void prep_weights(const float* __restrict__ W_al,
                             const float* __restrict__ W_self,
                             const float* __restrict__ W_oth,
                             const float* __restrict__ W_ao,
                             const float* __restrict__ W_emb,
                             const float* __restrict__ W_out,
                             bf16x8* __restrict__ ws)
{
    const int u = blockIdx.x;     // 120 units
    const int l = threadIdx.x;    // 64 lanes
    const int s = l >> 4, col = l & 15;
    const float* W; int K, N, ld, c, t, shift = 0;
    if (u < 108)      { c = u / 3;         t = u % 3;         W = W_al;   K = 1129; N = 40; ld = 40; }
    else if (u < 112) { c = (u - 108) / 2; t = (u - 108) & 1; W = W_self; K = 37;   N = 32; ld = 32; }
    else if (u < 114) { c = 0;             t = u - 112;       W = W_oth;  K = 28;   N = 32; ld = 32; shift = 1; }
    else if (u < 116) { c = 0;             t = u - 114;       W = W_ao;   K = 32;   N = 32; ld = 32; }
    else if (u < 118) { c = 0;             t = u - 116;       W = W_emb;  K = 32;   N = 32; ld = 32; }
    else              { c = 0;             t = u - 118;       W = W_out;  K = 32;   N = 21; ld = 21; }
    const int j = t * 16 + col;
    bf16x8 h, lo;
#pragma unroll
    for (int i = 0; i < 8; ++i) {
        int k = c * 32 + s * 8 + i;
        int kk = k - shift;
        float w = (kk >= 0 && kk < K && j < N) ? W[kk * ld + j] : 0.f;
        __bf16 hb = (__bf16)w;
        h[i]  = hb;
        lo[i] = (__bf16)(w - (float)hb);
    }
    ws[u * 128 + l]      = h;
    ws[u * 128 + 64 + l] = lo;
}

// ---------------- main kernel: 256 threads (4 waves), 64 rows ----------------
__global__ __launch_bounds__(256, 3)
void qnet_fwd(const float* __restrict__ obs,
              const float* __restrict__ b_al,
              const float* __restrict__ b_ao,
              const float* __restrict__ b_emb,
              const float* __restrict__ b_out,
              const bf16x8* __restrict__ wf,
              float* __restrict__ out)
{
    // arena: pass1 A tri [0,24K) (3 bufs x 4 waves x 2KB), B tri [24K,42K);
    // pass2: pair dbufs at wv*8192 (2x4KB); head reuses wv*8192.
    __shared__ __align__(16) char arena[43008];
    __shared__ float sW[4 * 656];               // per-wave att weights [16][41]

    const int t    = threadIdx.x;
    const int lane = t & 63;
    const int wv   = t >> 6;
    const int s    = lane >> 4;
    const int cq   = lane & 15;
    const int rowbase = blockIdx.x * 64 + wv * 16;
    const float* __restrict__ orow = obs + (size_t)(rowbase + cq) * OBS;
    const char* __restrict__ wfb = (const char*)wf;
    float* __restrict__ sWw = sW + wv * 656;

    const f32x4 zf = {0.f, 0.f, 0.f, 0.f};

    // per-lane global source base (floats): row = cq, quad = s
    const size_t aBase = (size_t)(rowbase + cq) * OBS + 4 * s;
    // read offset for (row=cq, c4=2s); second half at +256
    const unsigned offA0 = (unsigned)((((2 * s) >> 2) << 10) + (((2 * s) & 3) << 8) + cq * 16);

    char* const A0 = arena + wv * 2048;         // + k*8192, k=0..2
    char* const B0 = arena + 24576;             // + k*6144, k=0..2

#define STAGE_A(DST, C)                                                           \
    do {                                                                          \
        glds16(obs + aBase + 32 * (C),      (DST));                               \
        glds16(obs + aBase + 32 * (C) + 16, (DST) + 1024);                        \
    } while (0)
#define STAGE_BC(DST, C)                                                          \
    do {                                                                          \
        const char* _bs = wfb + (size_t)(C) * 6144;                               \
        glds16(_bs + wv * 1024 + lane * 16, (DST) + wv * 1024);                   \
        glds16(_bs + (4 + (wv & 1)) * 1024 + lane * 16,                           \
               (DST) + (4 + (wv & 1)) * 1024);                                    \
    } while (0)

    // ================= pass 1: logits = obs @ W_al =================
    f32x4 acc0 = zf, acc1 = zf, acc2 = zf;

#define P1_MATH(FA0, FA1, BP)                                                     \
    do {                                                                          \
        float _av[8] = {(FA0).x, (FA0).y, (FA0).z, (FA0).w,                       \
                        (FA1).x, (FA1).y, (FA1).z, (FA1).w};                      \
        bf16x8 _ah, _al; split8(_av, _ah, _al);                                   \
        const char* _bp = (const char*)(BP);                                      \
        bf16x8 b0h = *(const bf16x8*)(_bp + lane * 16);                           \
        bf16x8 b0l = *(const bf16x8*)(_bp + 1024 + lane * 16);                    \
        bf16x8 b1h = *(const bf16x8*)(_bp + 2048 + lane * 16);                    \
        bf16x8 b1l = *(const bf16x8*)(_bp + 3072 + lane * 16);                    \
        bf16x8 b2h = *(const bf16x8*)(_bp + 4096 + lane * 16);                    \
        bf16x8 b2l = *(const bf16x8*)(_bp + 5120 + lane * 16);                    \
        __builtin_amdgcn_s_setprio(1);                                            \
        acc0 = mm3(_ah, _al, b0h, b0l, acc0);                                     \
        acc1 = mm3(_ah, _al, b1h, b1l, acc1);                                     \
        acc2 = mm3(_ah, _al, b2h, b2l, acc2);                                     \
        __builtin_amdgcn_s_setprio(0);                                            \
    } while (0)

    STAGE_A(A0, 0);        STAGE_BC(B0, 0);
    STAGE_A(A0 + 8192, 1); STAGE_BC(B0 + 6144, 1);

    for (int c = 0; c < 33; ++c) {
        const int kc = c % 3, kn = (c + 2) % 3;
        asm volatile("s_waitcnt vmcnt(4)" ::: "memory");
        __builtin_amdgcn_s_barrier();
        __builtin_amdgcn_sched_barrier(0);
        const char* ab = A0 + kc * 8192;
        float4 fa0 = *(const float4*)(ab + offA0);
        float4 fa1 = *(const float4*)(ab + offA0 + 256);
        STAGE_A(A0 + kn * 8192, c + 2);         // tri-buffer: no read hazard
        STAGE_BC(B0 + kn * 6144, c + 2);        // overwrites B(c-1): readers done
        P1_MATH(fa0, fa1, B0 + kc * 6144);
    }
    {   // c = 33: stage only B(35)
        asm volatile("s_waitcnt vmcnt(4)" ::: "memory");
        __builtin_amdgcn_s_barrier();
        __builtin_amdgcn_sched_barrier(0);
        const char* ab = A0 + (33 % 3) * 8192;
        float4 fa0 = *(const float4*)(ab + offA0);
        float4 fa1 = *(const float4*)(ab + offA0 + 256);
        STAGE_BC(B0 + (35 % 3) * 6144, 35);
        P1_MATH(fa0, fa1, B0 + (33 % 3) * 6144);
    }
    {   // c = 34
        asm volatile("s_waitcnt vmcnt(2)" ::: "memory");
        __builtin_amdgcn_s_barrier();
        __builtin_amdgcn_sched_barrier(0);
        const char* ab = A0 + (34 % 3) * 8192;
        float4 fa0 = *(const float4*)(ab + offA0);
        float4 fa1 = *(const float4*)(ab + offA0 + 256);
        P1_MATH(fa0, fa1, B0 + (34 % 3) * 6144);
    }
    {   // c = 35: masked A tail via VGPR loads
        asm volatile("s_waitcnt vmcnt(0)" ::: "memory");
        __builtin_amdgcn_s_barrier();
        __builtin_amdgcn_sched_barrier(0);
        float av[8] = {0, 0, 0, 0, 0, 0, 0, 0};
        if (s == 0) {
            float4 p = ld4(orow + 1120), q = ld4(orow + 1124);
            av[0] = p.x; av[1] = p.y; av[2] = p.z; av[3] = p.w;
            av[4] = q.x; av[5] = q.y; av[6] = q.z; av[7] = q.w;
        } else if (s == 1) {
            av[0] = orow[1128];
        }
        float4 fa0 = {av[0], av[1], av[2], av[3]};
        float4 fa1 = {av[4], av[5], av[6], av[7]};
        P1_MATH(fa0, fa1, B0 + (35 % 3) * 6144);
    }
    __syncthreads();   // arena handoff to pass 2

    // ===== softmax over 40 cols (intra-wave; C rows: row = 4s+j) =====
    {
        const float bal0 = b_al[cq];
        const float bal1 = b_al[16 + cq];
        const bool  v2m  = (cq < 8);
        const float bal2 = v2m ? b_al[32 + cq] : 0.f;
#pragma unroll
        for (int j = 0; j < 4; ++j) {
            float v0 = acc0[j] + bal0, v1 = acc1[j] + bal1, vv = acc2[j] + bal2;
            float m = fmaxf(fmaxf(v0, v1), v2m ? vv : -3.4e38f);
#pragma unroll
            for (int d = 1; d < 16; d <<= 1) m = fmaxf(m, __shfl_xor(m, d));
            float e0 = __expf(v0 - m), e1 = __expf(v1 - m);
            float e2 = v2m ? __expf(vv - m) : 0.f;
            float sm = e0 + e1 + e2;
#pragma unroll
            for (int d = 1; d < 16; d <<= 1) sm += __shfl_xor(sm, d);
            float inv = 1.f / sm;
            const int row = s * 4 + j;
            sWw[row * 41 + cq]      = e0 * inv;
            sWw[row * 41 + 16 + cq] = e1 * inv;
            if (v2m) sWw[row * 41 + 32 + cq] = e2 * inv;
        }
    }
    // no barrier: sWw wave-private

    // ================= pass 2: encodings, weighted sum =================
    const bf16x8* bo = wf + (size_t)112 * 128;
    const bf16x8 Boh0 = bo[lane],       Bol0 = bo[64 + lane];
    const bf16x8 Boh1 = bo[128 + lane], Bol1 = bo[192 + lane];

    f32x4 at0 = zf, at1 = zf;
    {   // self encoding (no relu), 3-term, weight att_w[row][0]
        f32x4 e0 = zf, e1 = zf;
        {
            float4 p = ld4(orow + s * 8), q = ld4(orow + s * 8 + 4);
            float av[8] = {p.x, p.y, p.z, p.w, q.x, q.y, q.z, q.w};
            bf16x8 ah, al; split8(av, ah, al);
            const bf16x8* bu = wf + (size_t)108 * 128;
            e0 = mm3(ah, al, bu[lane],       bu[64 + lane],  e0);
            e1 = mm3(ah, al, bu[128 + lane], bu[192 + lane], e1);
        }
        {
            float av[8] = {0, 0, 0, 0, 0, 0, 0, 0};
            if (s == 0) {
                float4 p = ld4(orow + 32);
                av[0] = p.x; av[1] = p.y; av[2] = p.z; av[3] = p.w;
                av[4] = orow[36];
            }
            bf16x8 ah, al; split8(av, ah, al);
            const bf16x8* bu = wf + (size_t)110 * 128;
            e0 = mm3(ah, al, bu[lane],       bu[64 + lane],  e0);
            e1 = mm3(ah, al, bu[128 + lane], bu[192 + lane], e1);
        }
#pragma unroll
        for (int j = 0; j < 4; ++j) {
            float w0 = sWw[(s * 4 + j) * 41];
            at0[j] = w0 * e0[j];
            at1[j] = w0 * e1[j];
        }
    }

    // ---- other agents 0..37 via wave-private glds16 dbuf staging ----
    asm volatile("s_waitcnt vmcnt(0)" ::: "memory");   // clean slate for counting

    const size_t pBase = (size_t)(rowbase + cq) * OBS + 36 + 4 * s;
    const unsigned oP00 = offA0;   // c4 = 2s (within 4KB pair buffer)
    const unsigned oP10 = (unsigned)((((7 + 2 * s) >> 2) << 10) + (((7 + 2 * s) & 3) << 8) + cq * 16);
    const unsigned oP11 = (unsigned)((((8 + 2 * s) >> 2) << 10) + (((8 + 2 * s) & 3) << 8) + cq * 16);

#define STAGE_P(DST, P)                                                           \
    do {                                                                          \
        glds16(obs + pBase + 56 * (P),      (DST));                               \
        glds16(obs + pBase + 56 * (P) + 16, (DST) + 1024);                        \
        glds16(obs + pBase + 56 * (P) + 32, (DST) + 2048);                        \
        glds16(obs + pBase + 56 * (P) + 48, (DST) + 3072);                        \
    } while (0)

    char* q0 = arena + wv * 8192;
    char* q1 = q0 + 4096;
    STAGE_P(q0, 0);
    STAGE_P(q1, 1);

#define PROC2(N, U0, U1)                                                          \
    do {                                                                          \
        bf16x8 _ah;                                                               \
        _ah[0] = (__bf16)(U0).x; _ah[1] = (__bf16)(U0).y;                         \
        _ah[2] = (__bf16)(U0).z; _ah[3] = (__bf16)(U0).w;                         \
        _ah[4] = (__bf16)(U1).x; _ah[5] = (__bf16)(U1).y;                         \
        _ah[6] = (__bf16)(U1).z; _ah[7] = (__bf16)(U1).w;                         \
        f32x4 _e0 = MFMA(_ah, Boh0, zf); _e0 = MFMA(_ah, Bol0, _e0);              \
        f32x4 _e1 = MFMA(_ah, Boh1, zf); _e1 = MFMA(_ah, Bol1, _e1);              \
        _Pragma("unroll")                                                         \
        for (int _j = 0; _j < 4; ++_j) {                                          \
            float _wn = sWw[(s * 4 + _j) * 41 + 1 + (N)];                         \
            at0[_j] += _wn * fmaxf(_e0[_j], 0.f);                                 \
            at1[_j] += _wn * fmaxf(_e1[_j], 0.f);                                 \
        }                                                                         \
    } while (0)

    for (int p = 0; p < 17; ++p) {
        asm volatile("s_waitcnt vmcnt(4)" ::: "memory");
        __builtin_amdgcn_sched_barrier(0);
        float4 u00 = *(const float4*)(q0 + oP00);
        float4 u01 = *(const float4*)(q0 + oP00 + 256);
        float4 u10 = *(const float4*)(q0 + oP10);
        float4 u11 = *(const float4*)(q0 + oP11);
        asm volatile("s_waitcnt lgkmcnt(0)" ::: "memory");
        __builtin_amdgcn_sched_barrier(0);
        STAGE_P(q0, p + 2);                   // overwrite own drained buf
        __builtin_amdgcn_s_setprio(1);
        PROC2(2 * p,     u00, u01);
        PROC2(2 * p + 1, u10, u11);
        __builtin_amdgcn_s_setprio(0);
        char* tq = q0; q0 = q1; q1 = tq;
    }
    {   // p = 17
        asm volatile("s_waitcnt vmcnt(4)" ::: "memory");
        __builtin_amdgcn_sched_barrier(0);
        float4 u00 = *(const float4*)(q0 + oP00);
        float4 u01 = *(const float4*)(q0 + oP00 + 256);
        float4 u10 = *(const float4*)(q0 + oP10);
        float4 u11 = *(const float4*)(q0 + oP11);
        PROC2(34, u00, u01);
        PROC2(35, u10, u11);
        char* tq = q0; q0 = q1; q1 = tq;
    }
    {   // p = 18
        asm volatile("s_waitcnt vmcnt(0)" ::: "memory");
        __builtin_amdgcn_sched_barrier(0);
        float4 u00 = *(const float4*)(q0 + oP00);
        float4 u01 = *(const float4*)(q0 + oP00 + 256);
        float4 u10 = *(const float4*)(q0 + oP10);
        float4 u11 = *(const float4*)(q0 + oP11);
        PROC2(36, u00, u01);
        PROC2(37, u10, u11);
    }
    {   // agent 38 via VGPR loads (virtual k=0 pad row in W_oth')
        const float* op = orow + 1100;        // col 36 + 28*38
        float av[8];
        if (s < 3) {
            float4 p = ld4(op + s * 8), q = ld4(op + s * 8 + 4);
            av[0] = p.x; av[1] = p.y; av[2] = p.z; av[3] = p.w;
            av[4] = q.x; av[5] = q.y; av[6] = q.z; av[7] = q.w;
        } else {
            float4 p = ld4(op + 24);
            av[0] = p.x; av[1] = p.y; av[2] = p.z; av[3] = p.w;
            av[4] = op[28];
            av[5] = 0.f; av[6] = 0.f; av[7] = 0.f;
        }
        float4 u0 = {av[0], av[1], av[2], av[3]};
        float4 u1 = {av[4], av[5], av[6], av[7]};
        PROC2(38, u0, u1);
    }

    // ============ head: 3 dense layers, wave-private LDS (arena reuse) ============
    __bf16* hiw = (__bf16*)(arena + wv * 8192);
    __bf16* low = hiw + 640;
    f32x4 x0 = at0, x1 = at1;
#pragma unroll
    for (int L = 0; L < 3; ++L) {
        const int unit = 114 + L * 2;
        const float* bias = (L == 0) ? b_ao : (L == 1) ? b_emb : b_out;
        const int N = (L == 2) ? 21 : 32;
#pragma unroll
        for (int j = 0; j < 4; ++j) {
            const int row = s * 4 + j;
            __bf16 h0 = (__bf16)x0[j];
            hiw[row * 40 + cq] = h0;
            low[row * 40 + cq] = (__bf16)(x0[j] - (float)h0);
            __bf16 h1 = (__bf16)x1[j];
            hiw[row * 40 + 16 + cq] = h1;
            low[row * 40 + 16 + cq] = (__bf16)(x1[j] - (float)h1);
        }
        bf16x8 ah = *(const bf16x8*)&hiw[cq * 40 + s * 8];
        bf16x8 al = *(const bf16x8*)&low[cq * 40 + s * 8];
        const bf16x8* bu = wf + (size_t)unit * 128;
        f32x4 y0 = mm3(ah, al, bu[lane],       bu[64 + lane],  zf);
        f32x4 y1 = mm3(ah, al, bu[128 + lane], bu[192 + lane], zf);
        const float bc0 = bias[cq];
        const float bc1 = (16 + cq < N) ? bias[16 + cq] : 0.f;
#pragma unroll
        for (int j = 0; j < 4; ++j) {
            y0[j] += bc0;
            y1[j] += bc1;
            if (L < 2) { y0[j] = fmaxf(y0[j], 0.f); y1[j] = fmaxf(y1[j], 0.f); }
        }
        x0 = y0; x1 = y1;
    }

#pragma unroll
    for (int j = 0; j < 4; ++j) {
        const int row = rowbase + s * 4 + j;
        out[(size_t)row * 21 + cq] = x0[j];
        if (cq < 5) out[(size_t)row * 21 + 16 + cq] = x1[j];
    }
}

extern "C" void kernel_launch(void* const* d_in, const int* in_sizes, int n_in,
                              void* d_out, int out_size, void* d_ws, size_t ws_size,
                              hipStream_t stream) {
    const float* obs    = (const float*)d_in[0];
    const float* W_al   = (const float*)d_in[1];
    const float* b_al   = (const float*)d_in[2];
    const float* W_self = (const float*)d_in[3];
    const float* W_oth  = (const float*)d_in[5];
    const float* W_ao   = (const float*)d_in[7];
    const float* b_ao   = (const float*)d_in[8];
    const float* W_emb  = (const float*)d_in[9];
    const float* b_emb  = (const float*)d_in[10];
    const float* W_out  = (const float*)d_in[11];
    const float* b_out  = (const float*)d_in[12];
    float* out = (float*)d_out;
    bf16x8* ws = (bf16x8*)d_ws;

    prep_weights<<<120, 64, 0, stream>>>(W_al, W_self, W_oth, W_ao, W_emb, W_out, ws);

    const int B = in_sizes[0] / OBS;        // 65536
    qnet_fwd<<<B / 64, 256, 0, stream>>>(obs, b_al, b_ao, b_emb, b_out,
                                         (const bf16x8*)ws, out);
}

// Round 9
// 112.818 us; speedup vs baseline: 1.3340x; 1.3340x over previous
//
#include <hip/hip_runtime.h>

// QNet forward, MI355X — R9: coalesced glds staging + LDS transpose.
// B=65536 rows, obs=1129 (37 self + 39*28 others).
// 256 thr (4 waves), 64 rows/block (16/wave), grid 1024, 2 blocks/CU (~68KB LDS).
//
// R8 post-mortem: every obs load was lane=row scattered -> 64 cache lines per
// wave instruction -> per-CU address-processing bound (warm==cold, nothing
// else saturated). R9 stages COALESCED: a wave instruction reads contiguous
// 16B units from 8 (pass1) / 4 (pass2) rows -> ~16-24 line-groups/instr.
// MFMA A-fragments are recovered from LDS via XOR-swizzled positions
// (pre-swizzled global SOURCE, linear LDS dest = guide T2/m173 pattern):
//   LDS[row][unit pos p] holds global unit p ^ (row&7); reader wants global
//   unit g of row r -> reads pos g^(r&7). Involution, coalescing-preserving.
// Pass 1: A [16][32]f tiles, quad-buffered, 2 glds16/chunk/wave; B frags
//   quad-buffered, 2 glds16/chunk/wave; vmcnt(8) + s_barrier per chunk
//   (lookahead 2, never drain). Chunk 35 (k>=1120) peeled to VGPR path.
// Pass 2: [16][64]f windows (2 agents), wave-private tri-buffer, 4 glds16,
//   vmcnt(8), no barriers. Agent 38 peeled to VGPR path.
//
// Fragment maps (gfx950 16x16x32 bf16): A/B: row|col = lane&15, k = 8*(lane>>4)+i
//   C/D: col = lane&15, row = 4*(lane>>4) + reg
// Split-bf16: 3-term logits/self/head, 2-term others.
//
// d_ws: 120 units of 128 bf16x8 (64 hi + 64 lo), 2KB each.
//   W_al: c*3+t | W_self: 108+c*2+t | W_oth'(K=32, leading zero row): 112+t
//   W_ao: 114+t | W_emb: 116+t | W_out: 118+t

typedef __bf16 bf16x8 __attribute__((ext_vector_type(8)));
typedef float  f32x4  __attribute__((ext_vector_type(4)));

constexpr int OBS = 1129;

#define MFMA(a, b, c) __builtin_amdgcn_mfma_f32_16x16x32_bf16((a), (b), (c), 0, 0, 0)

__device__ __forceinline__ float4 ld4(const float* p) {
    float4 v;
    __builtin_memcpy(&v, p, 16);
    return v;
}

__device__ __forceinline__ void split8(const float* a, bf16x8& h, bf16x8& l) {
#pragma unroll
    for (int i = 0; i < 8; ++i) {
        __bf16 hb = (__bf16)a[i];
        h[i] = hb;
        l[i] = (__bf16)(a[i] - (float)hb);
    }
}

__device__ __forceinline__ f32x4 mm3(bf16x8 ah, bf16x8 al, bf16x8 bh, bf16x8 bl, f32x4 c) {
    c = MFMA(ah, bh, c);
    c = MFMA(ah, bl, c);
    c = MFMA(al, bh, c);
    return c;
}

__device__ __forceinline__ void glds16(const void* g, void* l) {
    __builtin_amdgcn_global_load_lds((const __attribute__((address_space(1))) void*)g,
                                     (__attribute__((address_space(3))) void*)l, 16, 0, 0);
}

// ---------------- prep: split weights into fragment order ----------------
__global__ void prep_weights(const float* __restrict__ W_al,
                             const float* __restrict__ W_self,
                             const float* __restrict__ W_oth,
                             const float* __restrict__ W_ao,
                             const float* __restrict__ W_emb,
                             const float* __restrict__ W_out,
                             bf16x8* __restrict__ ws)
{
    const int u = blockIdx.x;     // 120 units
    const int l = threadIdx.x;    // 64 lanes
    const int s = l >> 4, col = l & 15;
    const float* W; int K, N, ld, c, t, shift = 0;
    if (u < 108)      { c = u / 3;         t = u % 3;         W = W_al;   K = 1129; N = 40; ld = 40; }
    else if (u < 112) { c = (u - 108) / 2; t = (u - 108) & 1; W = W_self; K = 37;   N = 32; ld = 32; }
    else if (u < 114) { c = 0;             t = u - 112;       W = W_oth;  K = 28;   N = 32; ld = 32; shift = 1; }
    else if (u < 116) { c = 0;             t = u - 114;       W = W_ao;   K = 32;   N = 32; ld = 32; }
    else if (u < 118) { c = 0;             t = u - 116;       W = W_emb;  K = 32;   N = 32; ld = 32; }
    else              { c = 0;             t = u - 118;       W = W_out;  K = 32;   N = 21; ld = 21; }
    const int j = t * 16 + col;
    bf16x8 h, lo;
#pragma unroll
    for (int i = 0; i < 8; ++i) {
        int k = c * 32 + s * 8 + i;
        int kk = k - shift;
        float w = (kk >= 0 && kk < K && j < N) ? W[kk * ld + j] : 0.f;
        __bf16 hb = (__bf16)w;
        h[i]  = hb;
        lo[i] = (__bf16)(w - (float)hb);
    }
    ws[u * 128 + l]      = h;
    ws[u * 128 + 64 + l] = lo;
}

// ---------------- main kernel: 256 threads (4 waves), 64 rows ----------------
__global__ __launch_bounds__(256, 2)
void qnet_fwd(const float* __restrict__ obs,
              const float* __restrict__ b_al,
              const float* __restrict__ b_ao,
              const float* __restrict__ b_emb,
              const float* __restrict__ b_out,
              const bf16x8* __restrict__ wf,
              float* __restrict__ out)
{
    // arena layout:
    //  pass1: A quad-buf [0,32768): buf k at k*8192, wave slice +wv*2048 (2KB tile)
    //         B quad-buf [32768,57344): buf k at 32768+k*6144
    //  pass2: wave-private tri-buf at wv*12288 (3 x 4KB windows); head reuses it
    __shared__ __align__(16) char arena[57344];
    __shared__ float sW[4 * 656];               // per-wave att weights [16][41]

    const int t    = threadIdx.x;
    const int lane = t & 63;
    const int wv   = t >> 6;
    const int s    = lane >> 4;
    const int cq   = lane & 15;
    const int rowbase = blockIdx.x * 64 + wv * 16;
    const float* __restrict__ orow = obs + (size_t)(rowbase + cq) * OBS;
    const char* __restrict__ wfb = (const char*)wf;
    float* __restrict__ sWw = sW + wv * 656;

    const f32x4 zf = {0.f, 0.f, 0.f, 0.f};

    // ---- pass-1 A staging bases (coalesced, source-swizzled) ----
    // instr0: rows 0..7 (8 lanes/row), instr1: rows 8..15. usrc=(lane&7)^(lane>>3)
    const size_t aB0 = (size_t)(rowbase + (lane >> 3)) * OBS + 4 * ((lane & 7) ^ (lane >> 3));
    const size_t aB1 = aB0 + (size_t)8 * OBS;
    // A frag read positions (16B units within the row's 128B)
    const unsigned rdA0 = (unsigned)(cq * 128 + (((2 * s)     ^ (cq & 7)) << 4));
    const unsigned rdA1 = (unsigned)(cq * 128 + (((2 * s + 1) ^ (cq & 7)) << 4));

    char* const Abase = arena + wv * 2048;      // + k*8192
    char* const Bbase = arena + 32768;          // + k*6144

#define STAGE_A(K, C)                                                             \
    do {                                                                          \
        char* _d = Abase + (K) * 8192;                                            \
        glds16(obs + aB0 + (C) * 32, _d);                                         \
        glds16(obs + aB1 + (C) * 32, _d + 1024);                                  \
    } while (0)
#define STAGE_BC(K, C)                                                            \
    do {                                                                          \
        const char* _bs = wfb + (size_t)(C) * 6144;                               \
        char* _d = Bbase + (K) * 6144;                                            \
        glds16(_bs + wv * 1024 + lane * 16, _d + wv * 1024);                      \
        glds16(_bs + (4 + (wv & 1)) * 1024 + lane * 16, _d + (4 + (wv & 1)) * 1024); \
    } while (0)

    // ================= pass 1: logits = obs @ W_al =================
    f32x4 acc0 = zf, acc1 = zf, acc2 = zf;

#define P1_MATH(FA0, FA1, BP)                                                     \
    do {                                                                          \
        float _av[8] = {(FA0).x, (FA0).y, (FA0).z, (FA0).w,                       \
                        (FA1).x, (FA1).y, (FA1).z, (FA1).w};                      \
        bf16x8 _ah, _al; split8(_av, _ah, _al);                                   \
        const char* _bp = (const char*)(BP);                                      \
        bf16x8 b0h = *(const bf16x8*)(_bp + lane * 16);                           \
        bf16x8 b0l = *(const bf16x8*)(_bp + 1024 + lane * 16);                    \
        bf16x8 b1h = *(const bf16x8*)(_bp + 2048 + lane * 16);                    \
        bf16x8 b1l = *(const bf16x8*)(_bp + 3072 + lane * 16);                    \
        bf16x8 b2h = *(const bf16x8*)(_bp + 4096 + lane * 16);                    \
        bf16x8 b2l = *(const bf16x8*)(_bp + 5120 + lane * 16);                    \
        __builtin_amdgcn_s_setprio(1);                                            \
        acc0 = mm3(_ah, _al, b0h, b0l, acc0);                                     \
        acc1 = mm3(_ah, _al, b1h, b1l, acc1);                                     \
        acc2 = mm3(_ah, _al, b2h, b2l, acc2);                                     \
        __builtin_amdgcn_s_setprio(0);                                            \
    } while (0)

    // prologue: stage chunks 0,1,2 (12 vmem ops/wave)
    STAGE_A(0, 0); STAGE_BC(0, 0);
    STAGE_A(1, 1); STAGE_BC(1, 1);
    STAGE_A(2, 2); STAGE_BC(2, 2);

    // steady: compute c, stage c+3 (c+3 <= 34)
    for (int c = 0; c < 32; ++c) {
        const int kc = c & 3, kn = (c + 3) & 3;
        asm volatile("s_waitcnt vmcnt(8)" ::: "memory");   // chunk c complete
        __builtin_amdgcn_s_barrier();
        __builtin_amdgcn_sched_barrier(0);
        const char* ab = Abase + kc * 8192;
        float4 fa0 = *(const float4*)(ab + rdA0);
        float4 fa1 = *(const float4*)(ab + rdA1);
        asm volatile("s_waitcnt lgkmcnt(0)" ::: "memory");
        __builtin_amdgcn_sched_barrier(0);
        STAGE_A(kn, c + 3);
        STAGE_BC(kn, c + 3);
        P1_MATH(fa0, fa1, Bbase + kc * 6144);
    }
    {   // c = 32: also stage B(35) into buf 3 (chunk 31's buf, readers done)
        asm volatile("s_waitcnt vmcnt(8)" ::: "memory");
        __builtin_amdgcn_s_barrier();
        __builtin_amdgcn_sched_barrier(0);
        const char* ab = Abase + 0 * 8192;
        float4 fa0 = *(const float4*)(ab + rdA0);
        float4 fa1 = *(const float4*)(ab + rdA1);
        asm volatile("s_waitcnt lgkmcnt(0)" ::: "memory");
        __builtin_amdgcn_sched_barrier(0);
        STAGE_BC(3, 35);
        P1_MATH(fa0, fa1, Bbase + 0 * 6144);
    }
    {   // c = 33  (outstanding: 33(4), 34(4), B35(2) = 10 -> wait 6 retires 33)
        asm volatile("s_waitcnt vmcnt(6)" ::: "memory");
        __builtin_amdgcn_s_barrier();
        __builtin_amdgcn_sched_barrier(0);
        const char* ab = Abase + 1 * 8192;
        float4 fa0 = *(const float4*)(ab + rdA0);
        float4 fa1 = *(const float4*)(ab + rdA1);
        P1_MATH(fa0, fa1, Bbase + 1 * 6144);
    }
    {   // c = 34  (outstanding: 34(4), B35(2) -> wait 2 retires 34)
        asm volatile("s_waitcnt vmcnt(2)" ::: "memory");
        __builtin_amdgcn_s_barrier();
        __builtin_amdgcn_sched_barrier(0);
        const char* ab = Abase + 2 * 8192;
        float4 fa0 = *(const float4*)(ab + rdA0);
        float4 fa1 = *(const float4*)(ab + rdA1);
        P1_MATH(fa0, fa1, Bbase + 2 * 6144);
    }
    {   // c = 35: masked A tail (k=1120..1128) via VGPR loads; B35 in buf 3
        asm volatile("s_waitcnt vmcnt(0)" ::: "memory");
        __builtin_amdgcn_s_barrier();
        __builtin_amdgcn_sched_barrier(0);
        float av[8] = {0, 0, 0, 0, 0, 0, 0, 0};
        if (s == 0) {
            float4 p = ld4(orow + 1120), q = ld4(orow + 1124);
            av[0] = p.x; av[1] = p.y; av[2] = p.z; av[3] = p.w;
            av[4] = q.x; av[5] = q.y; av[6] = q.z; av[7] = q.w;
        } else if (s == 1) {
            av[0] = orow[1128];
        }
        float4 fa0 = {av[0], av[1], av[2], av[3]};
        float4 fa1 = {av[4], av[5], av[6], av[7]};
        P1_MATH(fa0, fa1, Bbase + 3 * 6144);
    }
    __syncthreads();   // arena handoff: pass-2 regions overlap other waves' bufs

    // ===== softmax over 40 cols (intra-wave; C rows: row = 4s+j) =====
    {
        const float bal0 = b_al[cq];
        const float bal1 = b_al[16 + cq];
        const bool  v2m  = (cq < 8);
        const float bal2 = v2m ? b_al[32 + cq] : 0.f;
#pragma unroll
        for (int j = 0; j < 4; ++j) {
            float v0 = acc0[j] + bal0, v1 = acc1[j] + bal1, vv = acc2[j] + bal2;
            float m = fmaxf(fmaxf(v0, v1), v2m ? vv : -3.4e38f);
#pragma unroll
            for (int d = 1; d < 16; d <<= 1) m = fmaxf(m, __shfl_xor(m, d));
            float e0 = __expf(v0 - m), e1 = __expf(v1 - m);
            float e2 = v2m ? __expf(vv - m) : 0.f;
            float sm = e0 + e1 + e2;
#pragma unroll
            for (int d = 1; d < 16; d <<= 1) sm += __shfl_xor(sm, d);
            float inv = 1.f / sm;
            const int row = s * 4 + j;
            sWw[row * 41 + cq]      = e0 * inv;
            sWw[row * 41 + 16 + cq] = e1 * inv;
            if (v2m) sWw[row * 41 + 32 + cq] = e2 * inv;
        }
    }
    // no barrier: sWw wave-private

    // ================= pass 2: encodings, weighted sum =================
    const bf16x8* bo = wf + (size_t)112 * 128;
    const bf16x8 Boh0 = bo[lane],       Bol0 = bo[64 + lane];
    const bf16x8 Boh1 = bo[128 + lane], Bol1 = bo[192 + lane];

    f32x4 at0 = zf, at1 = zf;
    {   // self encoding (no relu), 3-term, weight att_w[row][0]
        f32x4 e0 = zf, e1 = zf;
        {
            float4 p = ld4(orow + s * 8), q = ld4(orow + s * 8 + 4);
            float av[8] = {p.x, p.y, p.z, p.w, q.x, q.y, q.z, q.w};
            bf16x8 ah, al; split8(av, ah, al);
            const bf16x8* bu = wf + (size_t)108 * 128;
            e0 = mm3(ah, al, bu[lane],       bu[64 + lane],  e0);
            e1 = mm3(ah, al, bu[128 + lane], bu[192 + lane], e1);
        }
        {
            float av[8] = {0, 0, 0, 0, 0, 0, 0, 0};
            if (s == 0) {
                float4 p = ld4(orow + 32);
                av[0] = p.x; av[1] = p.y; av[2] = p.z; av[3] = p.w;
                av[4] = orow[36];
            }
            bf16x8 ah, al; split8(av, ah, al);
            const bf16x8* bu = wf + (size_t)110 * 128;
            e0 = mm3(ah, al, bu[lane],       bu[64 + lane],  e0);
            e1 = mm3(ah, al, bu[128 + lane], bu[192 + lane], e1);
        }
#pragma unroll
        for (int j = 0; j < 4; ++j) {
            float w0 = sWw[(s * 4 + j) * 41];
            at0[j] = w0 * e0[j];
            at1[j] = w0 * e1[j];
        }
    }

    // ---- other agents 0..37 via coalesced wave-private tri-buffer windows ----
    asm volatile("s_waitcnt vmcnt(0)" ::: "memory");   // clean slate for counting

    // window staging bases: instr pairs (rows 0-3 / 4-7 even/odd swizzle class)
    const unsigned uE = (unsigned)((lane & 15) ^ (lane >> 4));        // rows r: r&7 = lane>>4
    const unsigned uO = (unsigned)((lane & 15) ^ (4 + (lane >> 4)));  // rows r: r&7 = 4+lane>>4
    const size_t pE = (size_t)(rowbase +     (lane >> 4)) * OBS + 36 + 4 * uE;
    const size_t pO = (size_t)(rowbase + 4 + (lane >> 4)) * OBS + 36 + 4 * uO;
    const size_t p8 = (size_t)8 * OBS;

    char* const Pbase = arena + wv * 12288;   // 3 x 4KB wave-private

#define STAGE_P(K, W)                                                             \
    do {                                                                          \
        char* _d = Pbase + (K) * 4096;                                            \
        glds16(obs + pE + 56 * (W),      _d);                                     \
        glds16(obs + pO + 56 * (W),      _d + 1024);                              \
        glds16(obs + pE + p8 + 56 * (W), _d + 2048);                              \
        glds16(obs + pO + p8 + 56 * (W), _d + 3072);                              \
    } while (0)

    // frag read positions within [16][64]f window (16B units, row stride 256B)
    const unsigned rdP00 = (unsigned)(cq * 256 + (((2 * s)     ^ (cq & 7)) << 4));
    const unsigned rdP01 = (unsigned)(cq * 256 + (((2 * s + 1) ^ (cq & 7)) << 4));
    const unsigned rdP10 = (unsigned)(cq * 256 + (((7 + 2 * s) ^ (cq & 7)) << 4));
    const unsigned rdP11 = (unsigned)(cq * 256 + (((8 + 2 * s) ^ (cq & 7)) << 4));

#define PROC2(N, U0, U1)                                                          \
    do {                                                                          \
        bf16x8 _ah;                                                               \
        _ah[0] = (__bf16)(U0).x; _ah[1] = (__bf16)(U0).y;                         \
        _ah[2] = (__bf16)(U0).z; _ah[3] = (__bf16)(U0).w;                         \
        _ah[4] = (__bf16)(U1).x; _ah[5] = (__bf16)(U1).y;                         \
        _ah[6] = (__bf16)(U1).z; _ah[7] = (__bf16)(U1).w;                         \
        f32x4 _e0 = MFMA(_ah, Boh0, zf); _e0 = MFMA(_ah, Bol0, _e0);              \
        f32x4 _e1 = MFMA(_ah, Boh1, zf); _e1 = MFMA(_ah, Bol1, _e1);              \
        _Pragma("unroll")                                                         \
        for (int _j = 0; _j < 4; ++_j) {                                          \
            float _wn = sWw[(s * 4 + _j) * 41 + 1 + (N)];                         \
            at0[_j] += _wn * fmaxf(_e0[_j], 0.f);                                 \
            at1[_j] += _wn * fmaxf(_e1[_j], 0.f);                                 \
        }                                                                         \
    } while (0)

#define P2_READS(K)                                                               \
    const char* _q = Pbase + (K) * 4096;                                          \
    float4 u00 = *(const float4*)(_q + rdP00);                                    \
    float4 u01 = *(const float4*)(_q + rdP01);                                    \
    float4 u10 = *(const float4*)(_q + rdP10);                                    \
    float4 u11 = *(const float4*)(_q + rdP11)

    STAGE_P(0, 0);
    STAGE_P(1, 1);
    STAGE_P(2, 2);

    for (int w = 0; w < 16; ++w) {
        const int kc = w % 3, kn = (w + 3) % 3;
        asm volatile("s_waitcnt vmcnt(8)" ::: "memory");   // window w complete
        __builtin_amdgcn_sched_barrier(0);
        P2_READS(kc);
        asm volatile("s_waitcnt lgkmcnt(0)" ::: "memory");
        __builtin_amdgcn_sched_barrier(0);
        STAGE_P(kn, w + 3);                   // overwrites just-read buffer
        __builtin_amdgcn_s_setprio(1);
        PROC2(2 * w,     u00, u01);
        PROC2(2 * w + 1, u10, u11);
        __builtin_amdgcn_s_setprio(0);
    }
    {   // w = 16 (outstanding 17,18 after wait)
        asm volatile("s_waitcnt vmcnt(8)" ::: "memory");
        __builtin_amdgcn_sched_barrier(0);
        P2_READS(1);
        PROC2(32, u00, u01);
        PROC2(33, u10, u11);
    }
    {   // w = 17
        asm volatile("s_waitcnt vmcnt(4)" ::: "memory");
        __builtin_amdgcn_sched_barrier(0);
        P2_READS(2);
        PROC2(34, u00, u01);
        PROC2(35, u10, u11);
    }
    {   // w = 18
        asm volatile("s_waitcnt vmcnt(0)" ::: "memory");
        __builtin_amdgcn_sched_barrier(0);
        P2_READS(0);
        PROC2(36, u00, u01);
        PROC2(37, u10, u11);
    }
    {   // agent 38 via VGPR loads (virtual k=0 pad row in W_oth')
        const float* op = orow + 1100;        // col 36 + 28*38
        float av[8];
        if (s < 3) {
            float4 p = ld4(op + s * 8), q = ld4(op + s * 8 + 4);
            av[0] = p.x; av[1] = p.y; av[2] = p.z; av[3] = p.w;
            av[4] = q.x; av[5] = q.y; av[6] = q.z; av[7] = q.w;
        } else {
            float4 p = ld4(op + 24);
            av[0] = p.x; av[1] = p.y; av[2] = p.z; av[3] = p.w;
            av[4] = op[28];
            av[5] = 0.f; av[6] = 0.f; av[7] = 0.f;
        }
        float4 u0 = {av[0], av[1], av[2], av[3]};
        float4 u1 = {av[4], av[5], av[6], av[7]};
        PROC2(38, u0, u1);
    }

    // ============ head: 3 dense layers, wave-private LDS (Pbase reuse) ============
    __bf16* hiw = (__bf16*)Pbase;
    __bf16* low = hiw + 640;
    f32x4 x0 = at0, x1 = at1;
#pragma unroll
    for (int L = 0; L < 3; ++L) {
        const int unit = 114 + L * 2;
        const float* bias = (L == 0) ? b_ao : (L == 1) ? b_emb : b_out;
        const int N = (L == 2) ? 21 : 32;
#pragma unroll
        for (int j = 0; j < 4; ++j) {
            const int row = s * 4 + j;
            __bf16 h0 = (__bf16)x0[j];
            hiw[row * 40 + cq] = h0;
            low[row * 40 + cq] = (__bf16)(x0[j] - (float)h0);
            __bf16 h1 = (__bf16)x1[j];
            hiw[row * 40 + 16 + cq] = h1;
            low[row * 40 + 16 + cq] = (__bf16)(x1[j] - (float)h1);
        }
        bf16x8 ah = *(const bf16x8*)&hiw[cq * 40 + s * 8];
        bf16x8 al = *(const bf16x8*)&low[cq * 40 + s * 8];
        const bf16x8* bu = wf + (size_t)unit * 128;
        f32x4 y0 = mm3(ah, al, bu[lane],       bu[64 + lane],  zf);
        f32x4 y1 = mm3(ah, al, bu[128 + lane], bu[192 + lane], zf);
        const float bc0 = bias[cq];
        const float bc1 = (16 + cq < N) ? bias[16 + cq] : 0.f;
#pragma unroll
        for (int j = 0; j < 4; ++j) {
            y0[j] += bc0;
            y1[j] += bc1;
            if (L < 2) { y0[j] = fmaxf(y0[j], 0.f); y1[j] = fmaxf(y1[j], 0.f); }
        }
        x0 = y0; x1 = y1;
    }

#pragma unroll
    for (int j = 0; j < 4; ++j) {
        const int row = rowbase + s * 4 + j;
        out[(size_t)row * 21 + cq] = x0[j];
        if (cq < 5) out[(size_t)row * 21 + 16 + cq] = x1[j];
    }
}

extern "C" void kernel_launch(void* const* d_in, const int* in_sizes, int n_in,
                              void* d_out, int out_size, void* d_ws, size_t ws_size,
                              hipStream_t stream) {
    const float* obs    = (const float*)d_in[0];
    const float* W_al   = (const float*)d_in[1];
    const float* b_al   = (const float*)d_in[2];
    const float* W_self = (const float*)d_in[3];
    const float* W_oth  = (const float*)d_in[5];
    const float* W_ao   = (const float*)d_in[7];
    const float* b_ao   = (const float*)d_in[8];
    const float* W_emb  = (const float*)d_in[9];
    const float* b_emb  = (const float*)d_in[10];
    const float* W_out  = (const float*)d_in[11];
    const float* b_out  = (const float*)d_in[12];
    float* out = (float*)d_out;
    bf16x8* ws = (bf16x8*)d_ws;

    prep_weights<<<120, 64, 0, stream>>>(W_al, W_self, W_oth, W_ao, W_emb, W_out, ws);

    const int B = in_sizes[0] / OBS;        // 65536
    qnet_fwd<<<B / 64, 256, 0, stream>>>(obs, b_al, b_ao, b_emb, b_out,
                                         (const bf16x8*)ws, out);
}